// Round 1
// baseline (1195.882 us; speedup 1.0000x reference)
//
#include <hip/hip_runtime.h>
#include <math.h>

#define BSZ   2
#define TSEQ  2048
#define CDIM  1024
#define NHEAD 16
#define HDIM  64
#define BT    (BSZ*TSEQ)

// ---------------------------------------------------------------------------
// y = X @ W + bias ; X: MxK, W: KxN, y: MxN. M,N multiples of 64, K of 16.
// 64x64 block tile, 256 threads, 4x4 micro-tile, fp32.
// LDS rows padded to 68 floats (272 B) so 4-float reads are 16B-aligned b128.
// ---------------------------------------------------------------------------
__global__ __launch_bounds__(256) void gemm_bias_kernel(
    const float* __restrict__ X, const float* __restrict__ W,
    const float* __restrict__ bias, float* __restrict__ Y,
    int M, int N, int K)
{
    __shared__ __align__(16) float As[16][68];   // [k][m]
    __shared__ __align__(16) float Bs[16][68];   // [k][n]
    const int tid = threadIdx.x;
    const int bm = blockIdx.y * 64;
    const int bn = blockIdx.x * 64;
    const int tx = tid & 15, ty = tid >> 4;
    float acc[4][4] = {};

    for (int k0 = 0; k0 < K; k0 += 16) {
        #pragma unroll
        for (int i = 0; i < 4; ++i) {           // A tile: 64x16
            int idx = tid + i * 256;
            int m = idx >> 4, kk = idx & 15;
            As[kk][m] = X[(size_t)(bm + m) * K + k0 + kk];
        }
        #pragma unroll
        for (int i = 0; i < 4; ++i) {           // B tile: 16x64
            int idx = tid + i * 256;
            int kk = idx >> 6, n = idx & 63;
            Bs[kk][n] = W[(size_t)(k0 + kk) * N + bn + n];
        }
        __syncthreads();
        #pragma unroll
        for (int kk = 0; kk < 16; ++kk) {
            float a4[4], b4[4];
            #pragma unroll
            for (int i = 0; i < 4; ++i) a4[i] = As[kk][ty * 4 + i];
            #pragma unroll
            for (int j = 0; j < 4; ++j) b4[j] = Bs[kk][tx * 4 + j];
            #pragma unroll
            for (int i = 0; i < 4; ++i)
                #pragma unroll
                for (int j = 0; j < 4; ++j)
                    acc[i][j] = fmaf(a4[i], b4[j], acc[i][j]);
        }
        __syncthreads();
    }
    #pragma unroll
    for (int i = 0; i < 4; ++i) {
        int row = bm + ty * 4 + i;
        #pragma unroll
        for (int j = 0; j < 4; ++j) {
            int col = bn + tx * 4 + j;
            Y[(size_t)row * N + col] = acc[i][j] + bias[col];
        }
    }
}

// ---------------------------------------------------------------------------
// In-place RoPE per reference: t1=x[0:32], t2=x[32:64];
// out = [t1*cos + t2*sin, t1*sin - t2*cos]; ang = pos * 10000^(-j/32)
// ---------------------------------------------------------------------------
__global__ __launch_bounds__(256) void rope_kernel(float* __restrict__ t,
                                                   int nheads, int total)
{
    int idx = blockIdx.x * 256 + threadIdx.x;
    if (idx >= total) return;
    int j    = idx & 31;
    int rest = idx >> 5;
    int bt   = rest / nheads;
    int h    = rest - bt * nheads;
    int tpos = bt & (TSEQ - 1);
    // 10000^(-j/32) = 2^(-j * log2(10000)/32)
    float freq = exp2f(-0.41524101186092029f * (float)j);
    float ang = (float)tpos * freq;
    float s = sinf(ang), c = cosf(ang);
    float* base = t + ((size_t)bt * nheads + h) * HDIM;
    float a  = base[j];
    float b2 = base[j + 32];
    base[j]      = fmaf(a, c, b2 * s);
    base[j + 32] = fmaf(a, s, -b2 * c);
}

// ---------------------------------------------------------------------------
// Flash-style causal MQA. One block per (q-tile of 64 rows, head, batch).
// 256 threads = 16x16 grid of 4x4 micro-tiles. fp32, online softmax.
// q,o layout: [bt][h*64+d]; k,v layout: [bt][d].
// ---------------------------------------------------------------------------
__global__ __launch_bounds__(256) void flash_kernel(
    const float* __restrict__ q, const float* __restrict__ k,
    const float* __restrict__ v, float* __restrict__ o)
{
    const int qt = blockIdx.x;     // 0..31
    const int h  = blockIdx.y;     // 0..15
    const int b  = blockIdx.z;     // 0..1
    __shared__ __align__(16) float Qs[64][68];   // [d][qr]
    __shared__ __align__(16) float Ks[64][68];   // [d][kr]
    __shared__ __align__(16) float Vs[64][68];   // [kr][d]
    __shared__ __align__(16) float Ps[64][68];   // [kr][qr] (transposed scores)
    __shared__ float mrow[64], lrow[64], arow[64];
    const int tid = threadIdx.x;
    const int tx = tid & 15, ty = tid >> 4;
    const int qr0 = ty * 4, c0 = tx * 4;
    const size_t qbase = (((size_t)b * TSEQ + (size_t)qt * 64) * NHEAD + h) * HDIM;

    #pragma unroll
    for (int i = 0; i < 16; ++i) {
        int idx = tid + i * 256;            // 0..4095
        int qr = idx >> 6, d = idx & 63;
        Qs[d][qr] = q[qbase + (size_t)qr * (NHEAD * HDIM) + d];
    }
    if (tid < 64) { mrow[tid] = -3e38f; lrow[tid] = 0.f; }
    float acc[4][4] = {};

    for (int kt = 0; kt <= qt; ++kt) {
        const size_t kbase = ((size_t)b * TSEQ + (size_t)kt * 64) * HDIM;
        #pragma unroll
        for (int i = 0; i < 16; ++i) {
            int idx = tid + i * 256;        // idx = kr*64 + d
            int kr = idx >> 6, d = idx & 63;
            Ks[d][kr] = k[kbase + idx];
            Vs[kr][d] = v[kbase + idx];
        }
        __syncthreads();

        // S = Q.K^T (per-thread 4x4 over [qr][kr])
        float s4[4][4] = {};
        #pragma unroll 8
        for (int d = 0; d < 64; ++d) {
            float a4[4], b4[4];
            #pragma unroll
            for (int i = 0; i < 4; ++i) a4[i] = Qs[d][qr0 + i];
            #pragma unroll
            for (int j = 0; j < 4; ++j) b4[j] = Ks[d][c0 + j];
            #pragma unroll
            for (int i = 0; i < 4; ++i)
                #pragma unroll
                for (int j = 0; j < 4; ++j)
                    s4[i][j] = fmaf(a4[i], b4[j], s4[i][j]);
        }
        const bool diag = (kt == qt);
        #pragma unroll
        for (int j = 0; j < 4; ++j)
            #pragma unroll
            for (int i = 0; i < 4; ++i) {
                float val = s4[i][j] * 0.125f;   // 1/sqrt(64)
                if (diag && (c0 + j) > (qr0 + i)) val = -3e38f;
                Ps[c0 + j][qr0 + i] = val;
            }
        __syncthreads();

        // online softmax: one lane per q-row (wave 0 only, uniform branch)
        if (tid < 64) {
            const int r = tid;
            float m_old = mrow[r];
            float mx = m_old;
            #pragma unroll 8
            for (int j2 = 0; j2 < 64; ++j2) mx = fmaxf(mx, Ps[j2][r]);
            float alpha = __expf(m_old - mx);
            float sum = 0.f;
            #pragma unroll 8
            for (int j2 = 0; j2 < 64; ++j2) {
                float e = __expf(Ps[j2][r] - mx);
                Ps[j2][r] = e;
                sum += e;
            }
            lrow[r] = lrow[r] * alpha + sum;
            mrow[r] = mx;
            arow[r] = alpha;
        }
        __syncthreads();

        // O = O*alpha + P.V
        #pragma unroll
        for (int i = 0; i < 4; ++i) {
            float al = arow[qr0 + i];
            #pragma unroll
            for (int j = 0; j < 4; ++j) acc[i][j] *= al;
        }
        #pragma unroll 8
        for (int kr = 0; kr < 64; ++kr) {
            float p4[4], v4[4];
            #pragma unroll
            for (int i = 0; i < 4; ++i) p4[i] = Ps[kr][qr0 + i];
            #pragma unroll
            for (int j = 0; j < 4; ++j) v4[j] = Vs[kr][c0 + j];
            #pragma unroll
            for (int i = 0; i < 4; ++i)
                #pragma unroll
                for (int j = 0; j < 4; ++j)
                    acc[i][j] = fmaf(p4[i], v4[j], acc[i][j]);
        }
        __syncthreads();
    }

    #pragma unroll
    for (int i = 0; i < 4; ++i) {
        const int qr = qr0 + i;
        const float inv = 1.0f / lrow[qr];
        #pragma unroll
        for (int j = 0; j < 4; ++j)
            o[qbase + (size_t)qr * (NHEAD * HDIM) + c0 + j] = acc[i][j] * inv;
    }
}

// ---------------------------------------------------------------------------
extern "C" void kernel_launch(void* const* d_in, const int* in_sizes, int n_in,
                              void* d_out, int out_size, void* d_ws, size_t ws_size,
                              hipStream_t stream)
{
    const float* x  = (const float*)d_in[0];
    const float* Wq = (const float*)d_in[1];
    const float* bq = (const float*)d_in[2];
    const float* Wk = (const float*)d_in[3];
    const float* bk = (const float*)d_in[4];
    const float* Wv = (const float*)d_in[5];
    const float* bv = (const float*)d_in[6];
    const float* Wo = (const float*)d_in[7];
    const float* bo = (const float*)d_in[8];
    float* out = (float*)d_out;

    // workspace: q[BT*C] | k[BT*HD] | v[BT*HD] | ao[BT*C]  (~34 MB)
    float* q  = (float*)d_ws;
    float* kk = q  + (size_t)BT * CDIM;
    float* vv = kk + (size_t)BT * HDIM;
    float* ao = vv + (size_t)BT * HDIM;

    dim3 blk(256);

    // q = x@Wq + bq  (4096x1024x1024)
    gemm_bias_kernel<<<dim3(CDIM / 64, BT / 64), blk, 0, stream>>>(
        x, Wq, bq, q, BT, CDIM, CDIM);
    // k,v = x@W{k,v} + b  (4096x64x1024)
    gemm_bias_kernel<<<dim3(HDIM / 64, BT / 64), blk, 0, stream>>>(
        x, Wk, bk, kk, BT, HDIM, CDIM);
    gemm_bias_kernel<<<dim3(HDIM / 64, BT / 64), blk, 0, stream>>>(
        x, Wv, bv, vv, BT, HDIM, CDIM);

    // RoPE in place
    {
        int total_q = BT * NHEAD * (HDIM / 2);
        rope_kernel<<<dim3((total_q + 255) / 256), blk, 0, stream>>>(q, NHEAD, total_q);
        int total_k = BT * 1 * (HDIM / 2);
        rope_kernel<<<dim3((total_k + 255) / 256), blk, 0, stream>>>(kk, 1, total_k);
    }

    // causal MQA -> ao
    flash_kernel<<<dim3(TSEQ / 64, NHEAD, BSZ), blk, 0, stream>>>(q, kk, vv, ao);

    // out = ao@Wo + bo
    gemm_bias_kernel<<<dim3(CDIM / 64, BT / 64), blk, 0, stream>>>(
        ao, Wo, bo, out, BT, CDIM, CDIM);
}

// Round 2
// 620.136 us; speedup vs baseline: 1.9284x; 1.9284x over previous
//
#include <hip/hip_runtime.h>
#include <math.h>

#define BSZ   2
#define TSEQ  2048
#define CDIM  1024
#define NHEAD 16
#define HDIM  64
#define BT    (BSZ*TSEQ)
#define LDSS  72   // bf16 LDS row stride: 144 B = 16B-aligned, breaks pow2 banking

typedef __attribute__((ext_vector_type(8))) short short8;
typedef __attribute__((ext_vector_type(4))) float f32x4;

__device__ inline unsigned short f2b(float f) {
    union { float f; unsigned int u; } c; c.f = f;
    unsigned int u = c.u;
    u += 0x7fffu + ((u >> 16) & 1u);   // round-nearest-even
    return (unsigned short)(u >> 16);
}

// ---------------------------------------------------------------------------
// fp32 tiled GEMM with bias (unchanged from R1; replaced by MFMA next round)
// ---------------------------------------------------------------------------
__global__ __launch_bounds__(256) void gemm_bias_kernel(
    const float* __restrict__ X, const float* __restrict__ W,
    const float* __restrict__ bias, float* __restrict__ Y,
    int M, int N, int K)
{
    __shared__ __align__(16) float As[16][68];
    __shared__ __align__(16) float Bs[16][68];
    const int tid = threadIdx.x;
    const int bm = blockIdx.y * 64;
    const int bn = blockIdx.x * 64;
    const int tx = tid & 15, ty = tid >> 4;
    float acc[4][4] = {};

    for (int k0 = 0; k0 < K; k0 += 16) {
        #pragma unroll
        for (int i = 0; i < 4; ++i) {
            int idx = tid + i * 256;
            int m = idx >> 4, kk = idx & 15;
            As[kk][m] = X[(size_t)(bm + m) * K + k0 + kk];
        }
        #pragma unroll
        for (int i = 0; i < 4; ++i) {
            int idx = tid + i * 256;
            int kk = idx >> 6, n = idx & 63;
            Bs[kk][n] = W[(size_t)(k0 + kk) * N + bn + n];
        }
        __syncthreads();
        #pragma unroll
        for (int kk = 0; kk < 16; ++kk) {
            float a4[4], b4[4];
            #pragma unroll
            for (int i = 0; i < 4; ++i) a4[i] = As[kk][ty * 4 + i];
            #pragma unroll
            for (int j = 0; j < 4; ++j) b4[j] = Bs[kk][tx * 4 + j];
            #pragma unroll
            for (int i = 0; i < 4; ++i)
                #pragma unroll
                for (int j = 0; j < 4; ++j)
                    acc[i][j] = fmaf(a4[i], b4[j], acc[i][j]);
        }
        __syncthreads();
    }
    #pragma unroll
    for (int i = 0; i < 4; ++i) {
        int row = bm + ty * 4 + i;
        #pragma unroll
        for (int j = 0; j < 4; ++j) {
            int col = bn + tx * 4 + j;
            Y[(size_t)row * N + col] = acc[i][j] + bias[col];
        }
    }
}

// ---------------------------------------------------------------------------
// RoPE in place (fp32), per reference semantics
// ---------------------------------------------------------------------------
__global__ __launch_bounds__(256) void rope_kernel(float* __restrict__ t,
                                                   int nheads, int total)
{
    int idx = blockIdx.x * 256 + threadIdx.x;
    if (idx >= total) return;
    int j    = idx & 31;
    int rest = idx >> 5;
    int bt   = rest / nheads;
    int h    = rest - bt * nheads;
    int tpos = bt & (TSEQ - 1);
    float freq = exp2f(-0.41524101186092029f * (float)j);
    float ang = (float)tpos * freq;
    float s = sinf(ang), c = cosf(ang);
    float* base = t + ((size_t)bt * nheads + h) * HDIM;
    float a  = base[j];
    float b2 = base[j + 32];
    base[j]      = fmaf(a, c, b2 * s);
    base[j + 32] = fmaf(a, s, -b2 * c);
}

// ---------------------------------------------------------------------------
// MFMA flash attention (causal MQA). Block = 256 thr = 4 waves; 64 q-rows per
// block, wave w owns rows [w*16, w*16+16). Per 64-key tile:
//   QK: A=Q (m=q,k=d), B=K (n=key,k=d)  -> S in C-layout (col=lane&15,
//       row=quad*4+reg), 8 MFMAs (4 key-ntiles x 2 d-ktiles)
//   online softmax: quad-wide __shfl_xor reductions (masks 1,2,4,8)
//   P: C-layout -> LDS (bf16) -> A-layout reads (per-wave buffer, no barrier)
//   PV: A=P (m=q,k=key), B=V^T (n=d,k=key), V stored transposed [d][key]
// All bf16 LDS rows stride 72 (dword stride 36) -> frag b128 reads are 2-way.
// ---------------------------------------------------------------------------
__global__ __launch_bounds__(256) void flash_mfma_kernel(
    const float* __restrict__ q, const float* __restrict__ k,
    const float* __restrict__ v, float* __restrict__ o)
{
    const int qt = blockIdx.x;     // q tile 0..31
    const int h  = blockIdx.y;     // head
    const int b  = blockIdx.z;     // batch
    __shared__ __align__(16) unsigned short Qs[64 * LDSS];      // [qr][d]
    __shared__ __align__(16) unsigned short Ks[64 * LDSS];      // [key][d]
    __shared__ __align__(16) unsigned short Vs[64 * LDSS];      // [d][key] (transposed)
    __shared__ __align__(16) unsigned short Ps[4 * 16 * LDSS];  // per-wave [qr16][key]

    const int tid  = threadIdx.x;
    const int wave = tid >> 6, lane = tid & 63;
    const int ln16 = lane & 15, quad = lane >> 4;

    const size_t qbase = ((size_t)(b * TSEQ + qt * 64)) * CDIM + h * HDIM;

    // stage Q tile: 64 rows x 64 d, fp32 -> bf16
    #pragma unroll
    for (int i = 0; i < 4; ++i) {
        int lin = (tid + i * 256) * 4;         // 0..4095
        int qr = lin >> 6, d0 = lin & 63;
        float4 f = *(const float4*)&q[qbase + (size_t)qr * CDIM + d0];
        unsigned short* dst = &Qs[qr * LDSS + d0];
        dst[0] = f2b(f.x); dst[1] = f2b(f.y); dst[2] = f2b(f.z); dst[3] = f2b(f.w);
    }

    float m_r[4], l_r[4];
    f32x4 oacc[4];
    #pragma unroll
    for (int r = 0; r < 4; ++r) { m_r[r] = -1e30f; l_r[r] = 0.f; }
    #pragma unroll
    for (int t = 0; t < 4; ++t) oacc[t] = (f32x4){0.f, 0.f, 0.f, 0.f};

    unsigned short* Pw = &Ps[wave * 16 * LDSS];

    for (int kt = 0; kt <= qt; ++kt) {
        const size_t kb0 = ((size_t)(b * TSEQ + kt * 64)) * HDIM;
        // stage K [key][d] and V^T [d][key], fp32 -> bf16
        #pragma unroll
        for (int i = 0; i < 4; ++i) {
            int lin = (tid + i * 256) * 4;
            int kr = lin >> 6, d0 = lin & 63;
            float4 fk = *(const float4*)&k[kb0 + lin];
            unsigned short* dk = &Ks[kr * LDSS + d0];
            dk[0] = f2b(fk.x); dk[1] = f2b(fk.y); dk[2] = f2b(fk.z); dk[3] = f2b(fk.w);
            float4 fv = *(const float4*)&v[kb0 + lin];
            Vs[(d0 + 0) * LDSS + kr] = f2b(fv.x);
            Vs[(d0 + 1) * LDSS + kr] = f2b(fv.y);
            Vs[(d0 + 2) * LDSS + kr] = f2b(fv.z);
            Vs[(d0 + 3) * LDSS + kr] = f2b(fv.w);
        }
        __syncthreads();

        // ---- S = Q.K^T : 8 MFMAs ----
        f32x4 sv[4];
        #pragma unroll
        for (int t = 0; t < 4; ++t) sv[t] = (f32x4){0.f, 0.f, 0.f, 0.f};
        #pragma unroll
        for (int kk2 = 0; kk2 < 2; ++kk2) {
            short8 af = *(const short8*)&Qs[(wave * 16 + ln16) * LDSS + kk2 * 32 + quad * 8];
            #pragma unroll
            for (int t = 0; t < 4; ++t) {
                short8 bf = *(const short8*)&Ks[(t * 16 + ln16) * LDSS + kk2 * 32 + quad * 8];
                sv[t] = __builtin_amdgcn_mfma_f32_16x16x32_bf16(af, bf, sv[t], 0, 0, 0);
            }
        }

        // ---- scale + causal mask ----
        float sc[4][4];
        #pragma unroll
        for (int t = 0; t < 4; ++t)
            #pragma unroll
            for (int r = 0; r < 4; ++r)
                sc[t][r] = sv[t][r] * 0.125f;
        if (kt == qt) {
            #pragma unroll
            for (int t = 0; t < 4; ++t) {
                int key = t * 16 + ln16;
                #pragma unroll
                for (int r = 0; r < 4; ++r)
                    if (key > wave * 16 + quad * 4 + r) sc[t][r] = -1e30f;
            }
        }

        // ---- online softmax (quad-wide reductions) ----
        float alpha[4];
        #pragma unroll
        for (int r = 0; r < 4; ++r) {
            float mx = fmaxf(fmaxf(sc[0][r], sc[1][r]), fmaxf(sc[2][r], sc[3][r]));
            #pragma unroll
            for (int off = 1; off < 16; off <<= 1)
                mx = fmaxf(mx, __shfl_xor(mx, off, 64));
            float mnew = fmaxf(m_r[r], mx);
            alpha[r] = __expf(m_r[r] - mnew);
            m_r[r] = mnew;
            float srow = 0.f;
            #pragma unroll
            for (int t = 0; t < 4; ++t) {
                float e = __expf(sc[t][r] - mnew);
                sc[t][r] = e;
                srow += e;
            }
            #pragma unroll
            for (int off = 1; off < 16; off <<= 1)
                srow += __shfl_xor(srow, off, 64);
            l_r[r] = l_r[r] * alpha[r] + srow;
        }

        // ---- P -> per-wave LDS (C-layout scatter, bf16) ----
        #pragma unroll
        for (int t = 0; t < 4; ++t)
            #pragma unroll
            for (int r = 0; r < 4; ++r)
                Pw[(quad * 4 + r) * LDSS + t * 16 + ln16] = f2b(sc[t][r]);

        // ---- rescale O ----
        #pragma unroll
        for (int t = 0; t < 4; ++t)
            #pragma unroll
            for (int r = 0; r < 4; ++r)
                oacc[t][r] *= alpha[r];

        // ---- O += P.V : 8 MFMAs (per-wave P buffer; compiler orders LDS) ----
        #pragma unroll
        for (int kk2 = 0; kk2 < 2; ++kk2) {
            short8 pf = *(const short8*)&Pw[ln16 * LDSS + kk2 * 32 + quad * 8];
            #pragma unroll
            for (int t = 0; t < 4; ++t) {
                short8 vf = *(const short8*)&Vs[(t * 16 + ln16) * LDSS + kk2 * 32 + quad * 8];
                oacc[t] = __builtin_amdgcn_mfma_f32_16x16x32_bf16(pf, vf, oacc[t], 0, 0, 0);
            }
        }
        __syncthreads();   // before next staging overwrites Ks/Vs
    }

    // ---- epilogue: O / l ----
    float inv[4];
    #pragma unroll
    for (int r = 0; r < 4; ++r) inv[r] = 1.0f / l_r[r];
    #pragma unroll
    for (int t = 0; t < 4; ++t) {
        #pragma unroll
        for (int r = 0; r < 4; ++r) {
            int row = qt * 64 + wave * 16 + quad * 4 + r;
            int d   = t * 16 + ln16;
            o[((size_t)(b * TSEQ + row)) * CDIM + h * HDIM + d] = oacc[t][r] * inv[r];
        }
    }
}

// ---------------------------------------------------------------------------
extern "C" void kernel_launch(void* const* d_in, const int* in_sizes, int n_in,
                              void* d_out, int out_size, void* d_ws, size_t ws_size,
                              hipStream_t stream)
{
    const float* x  = (const float*)d_in[0];
    const float* Wq = (const float*)d_in[1];
    const float* bq = (const float*)d_in[2];
    const float* Wk = (const float*)d_in[3];
    const float* bk = (const float*)d_in[4];
    const float* Wv = (const float*)d_in[5];
    const float* bv = (const float*)d_in[6];
    const float* Wo = (const float*)d_in[7];
    const float* bo = (const float*)d_in[8];
    float* out = (float*)d_out;

    // workspace: q[BT*C] | k[BT*HD] | v[BT*HD] | ao[BT*C]  (~34 MB)
    float* q  = (float*)d_ws;
    float* kk = q  + (size_t)BT * CDIM;
    float* vv = kk + (size_t)BT * HDIM;
    float* ao = vv + (size_t)BT * HDIM;

    dim3 blk(256);

    gemm_bias_kernel<<<dim3(CDIM / 64, BT / 64), blk, 0, stream>>>(
        x, Wq, bq, q, BT, CDIM, CDIM);
    gemm_bias_kernel<<<dim3(HDIM / 64, BT / 64), blk, 0, stream>>>(
        x, Wk, bk, kk, BT, HDIM, CDIM);
    gemm_bias_kernel<<<dim3(HDIM / 64, BT / 64), blk, 0, stream>>>(
        x, Wv, bv, vv, BT, HDIM, CDIM);

    {
        int total_q = BT * NHEAD * (HDIM / 2);
        rope_kernel<<<dim3((total_q + 255) / 256), blk, 0, stream>>>(q, NHEAD, total_q);
        int total_k = BT * 1 * (HDIM / 2);
        rope_kernel<<<dim3((total_k + 255) / 256), blk, 0, stream>>>(kk, 1, total_k);
    }

    flash_mfma_kernel<<<dim3(TSEQ / 64, NHEAD, BSZ), blk, 0, stream>>>(q, kk, vv, ao);

    gemm_bias_kernel<<<dim3(CDIM / 64, BT / 64), blk, 0, stream>>>(
        ao, Wo, bo, out, BT, CDIM, CDIM);
}

// Round 3
// 367.439 us; speedup vs baseline: 3.2546x; 1.6877x over previous
//
#include <hip/hip_runtime.h>
#include <math.h>

#define BSZ   2
#define TSEQ  2048
#define CDIM  1024
#define NHEAD 16
#define HDIM  64
#define BT    (BSZ*TSEQ)
#define LDSS  72   // flash bf16 LDS row stride

typedef __attribute__((ext_vector_type(8))) short short8;
typedef __attribute__((ext_vector_type(4))) float f32x4;
typedef unsigned short u16;

__device__ __forceinline__ u16 f2b(float f) {
    union { float f; unsigned int u; } c; c.f = f;
    unsigned int u = c.u;
    u += 0x7fffu + ((u >> 16) & 1u);   // round-nearest-even
    return (u16)(u >> 16);
}

// async global->LDS, 16B per lane. LDS dest = wave-uniform base + lane*16.
__device__ __forceinline__ void async_copy16(const void* g, void* l) {
    __builtin_amdgcn_global_load_lds(
        (__attribute__((address_space(1))) const void*)g,
        (__attribute__((address_space(3))) void*)l,
        16, 0, 0);
}

// ---------------------------------------------------------------------------
// fp32 -> bf16 cast, 4 elems/thread
// ---------------------------------------------------------------------------
__global__ __launch_bounds__(256) void cast_bf16_kernel(
    const float* __restrict__ src, u16* __restrict__ dst, int n4)
{
    int i = blockIdx.x * 256 + threadIdx.x;
    if (i >= n4) return;
    float4 f = ((const float4*)src)[i];
    u16* d = dst + (size_t)i * 4;
    d[0] = f2b(f.x); d[1] = f2b(f.y); d[2] = f2b(f.z); d[3] = f2b(f.w);
}

// ---------------------------------------------------------------------------
// W [K][Nw] fp32 -> Wt [nofs+Nw][K] bf16 (transpose + cast). 64x64 LDS tile,
// pad 65 -> column re-read is 2-way (free).
// ---------------------------------------------------------------------------
__global__ __launch_bounds__(256) void transpose_cast_kernel(
    const float* __restrict__ W, u16* __restrict__ Wt,
    int K, int Nw, int nofs)
{
    __shared__ float T[64][65];
    const int tid = threadIdx.x;
    const int k0 = blockIdx.y * 64, n0 = blockIdx.x * 64;
    #pragma unroll
    for (int i = 0; i < 16; ++i) {
        int idx = i * 256 + tid, r = idx >> 6, c = idx & 63;
        T[r][c] = W[(size_t)(k0 + r) * Nw + n0 + c];
    }
    __syncthreads();
    #pragma unroll
    for (int i = 0; i < 16; ++i) {
        int idx = i * 256 + tid, rn = idx >> 6, ck = idx & 63;
        Wt[(size_t)(nofs + n0 + rn) * K + k0 + ck] = f2b(T[ck][rn]);
    }
}

__global__ void concat_bias_kernel(const float* __restrict__ bk,
                                   const float* __restrict__ bv,
                                   float* __restrict__ bkv)
{
    int t = threadIdx.x;   // 128
    bkv[t] = (t < 64) ? bk[t] : bv[t - 64];
}

// ---------------------------------------------------------------------------
// Y[M][N] fp32 = A[M][K](bf16) @ Bt[N][K](bf16)^T + bias.  TN MFMA GEMM.
// 64x128 tile, BK=32, 256 thr = 4 waves (2x2 of 32x64). global_load_lds
// stages chunk-ordered LDS: chunk i = [tile16][kquad][lane16] -> staging dest
// linear in lane (HW constraint) AND frag ds_read_b128 linear in lane
// (conflict-free), no padding needed.
// ---------------------------------------------------------------------------
__global__ __launch_bounds__(256) void gemm_mfma_kernel(
    const u16* __restrict__ A, const u16* __restrict__ Bt,
    const float* __restrict__ bias, float* __restrict__ Y,
    int M, int N, int K)
{
    __shared__ __align__(16) u16 AsC[64 * 32];    // 4 KB,  256 chunks
    __shared__ __align__(16) u16 BsC[128 * 32];   // 8 KB,  512 chunks
    const int tid  = threadIdx.x;
    const int wave = tid >> 6, lane = tid & 63;
    const int ln16 = lane & 15, quad = lane >> 4;
    const int wm = wave >> 1, wn = wave & 1;
    const int m0 = blockIdx.y * 64, n0 = blockIdx.x * 128;

    // staging: thread tid owns chunk tid (A), chunks tid and tid+256 (B)
    const int c_row = ((tid >> 6) << 4) + (tid & 15);   // sub-row within tile group
    const int c_k   = ((tid >> 4) & 3) * 8;             // k chunk offset (bf16)
    const u16* ag  = &A [(size_t)(m0 + c_row)       * K + c_k];
    const u16* bg0 = &Bt[(size_t)(n0 + c_row)       * K + c_k];
    const u16* bg1 = &Bt[(size_t)(n0 + 64 + c_row)  * K + c_k];
    u16* a_l  = &AsC[(size_t)wave * 64 * 8];            // wave-uniform bases
    u16* b_l0 = &BsC[(size_t)wave * 64 * 8];
    u16* b_l1 = &BsC[(size_t)(wave + 4) * 64 * 8];

    f32x4 acc[2][4];
    #pragma unroll
    for (int i = 0; i < 2; ++i)
        #pragma unroll
        for (int j = 0; j < 4; ++j) acc[i][j] = (f32x4){0.f, 0.f, 0.f, 0.f};

    for (int k0 = 0; k0 < K; k0 += 32) {
        async_copy16(ag,  a_l);
        async_copy16(bg0, b_l0);
        async_copy16(bg1, b_l1);
        ag += 32; bg0 += 32; bg1 += 32;
        __syncthreads();          // drains vmcnt (compiler-inserted)

        short8 af[2], bf[4];
        #pragma unroll
        for (int mt = 0; mt < 2; ++mt)
            af[mt] = *(const short8*)&AsC[(((wm * 2 + mt) * 64) + quad * 16 + ln16) * 8];
        #pragma unroll
        for (int nt = 0; nt < 4; ++nt)
            bf[nt] = *(const short8*)&BsC[(((wn * 4 + nt) * 64) + quad * 16 + ln16) * 8];
        #pragma unroll
        for (int mt = 0; mt < 2; ++mt)
            #pragma unroll
            for (int nt = 0; nt < 4; ++nt)
                acc[mt][nt] = __builtin_amdgcn_mfma_f32_16x16x32_bf16(
                    af[mt], bf[nt], acc[mt][nt], 0, 0, 0);
        __syncthreads();          // before next staging overwrites LDS
    }

    #pragma unroll
    for (int mt = 0; mt < 2; ++mt)
        #pragma unroll
        for (int nt = 0; nt < 4; ++nt) {
            int n = n0 + wn * 64 + nt * 16 + ln16;
            float bv = bias[n];
            #pragma unroll
            for (int r = 0; r < 4; ++r) {
                int m = m0 + wm * 32 + mt * 16 + quad * 4 + r;
                Y[(size_t)m * N + n] = acc[mt][nt][r] + bv;
            }
        }
}

// ---------------------------------------------------------------------------
// RoPE in place (fp32). base = t + bt*stride + h*64; rotates j and j+32.
// ---------------------------------------------------------------------------
__global__ __launch_bounds__(256) void rope_kernel(float* __restrict__ t,
                                                   int nheads, int stride, int total)
{
    int idx = blockIdx.x * 256 + threadIdx.x;
    if (idx >= total) return;
    int j    = idx & 31;
    int rest = idx >> 5;
    int bt   = rest / nheads;
    int h    = rest - bt * nheads;
    int tpos = bt & (TSEQ - 1);
    float freq = exp2f(-0.41524101186092029f * (float)j);  // 10000^(-j/32)
    float ang = (float)tpos * freq;
    float s = sinf(ang), c = cosf(ang);
    float* base = t + (size_t)bt * stride + h * HDIM;
    float a  = base[j];
    float b2 = base[j + 32];
    base[j]      = fmaf(a, c, b2 * s);
    base[j + 32] = fmaf(a, s, -b2 * c);
}

// ---------------------------------------------------------------------------
// MFMA flash attention (causal MQA), verified in R2. Changes: kv fused buffer
// (row stride 128: k = cols 0..63, v = 64..127) and bf16 output.
// ---------------------------------------------------------------------------
__global__ __launch_bounds__(256) void flash_mfma_kernel(
    const float* __restrict__ q, const float* __restrict__ kv,
    u16* __restrict__ o)
{
    const int qt = blockIdx.x;
    const int h  = blockIdx.y;
    const int b  = blockIdx.z;
    __shared__ __align__(16) u16 Qs[64 * LDSS];      // [qr][d]
    __shared__ __align__(16) u16 Ks[64 * LDSS];      // [key][d]
    __shared__ __align__(16) u16 Vs[64 * LDSS];      // [d][key]
    __shared__ __align__(16) u16 Ps[4 * 16 * LDSS];  // per-wave [qr16][key]

    const int tid  = threadIdx.x;
    const int wave = tid >> 6, lane = tid & 63;
    const int ln16 = lane & 15, quad = lane >> 4;

    const size_t qbase = ((size_t)(b * TSEQ + qt * 64)) * CDIM + h * HDIM;

    #pragma unroll
    for (int i = 0; i < 4; ++i) {
        int lin = (tid + i * 256) * 4;
        int qr = lin >> 6, d0 = lin & 63;
        float4 f = *(const float4*)&q[qbase + (size_t)qr * CDIM + d0];
        u16* dst = &Qs[qr * LDSS + d0];
        dst[0] = f2b(f.x); dst[1] = f2b(f.y); dst[2] = f2b(f.z); dst[3] = f2b(f.w);
    }

    float m_r[4], l_r[4];
    f32x4 oacc[4];
    #pragma unroll
    for (int r = 0; r < 4; ++r) { m_r[r] = -1e30f; l_r[r] = 0.f; }
    #pragma unroll
    for (int t = 0; t < 4; ++t) oacc[t] = (f32x4){0.f, 0.f, 0.f, 0.f};

    u16* Pw = &Ps[wave * 16 * LDSS];

    for (int kt = 0; kt <= qt; ++kt) {
        const size_t krow0 = (size_t)(b * TSEQ + kt * 64);
        #pragma unroll
        for (int i = 0; i < 4; ++i) {
            int lin = (tid + i * 256) * 4;
            int kr = lin >> 6, d0 = lin & 63;
            float4 fk = *(const float4*)&kv[(krow0 + kr) * 128 + d0];
            u16* dk = &Ks[kr * LDSS + d0];
            dk[0] = f2b(fk.x); dk[1] = f2b(fk.y); dk[2] = f2b(fk.z); dk[3] = f2b(fk.w);
            float4 fv = *(const float4*)&kv[(krow0 + kr) * 128 + 64 + d0];
            Vs[(d0 + 0) * LDSS + kr] = f2b(fv.x);
            Vs[(d0 + 1) * LDSS + kr] = f2b(fv.y);
            Vs[(d0 + 2) * LDSS + kr] = f2b(fv.z);
            Vs[(d0 + 3) * LDSS + kr] = f2b(fv.w);
        }
        __syncthreads();

        f32x4 sv[4];
        #pragma unroll
        for (int t = 0; t < 4; ++t) sv[t] = (f32x4){0.f, 0.f, 0.f, 0.f};
        #pragma unroll
        for (int kk2 = 0; kk2 < 2; ++kk2) {
            short8 af = *(const short8*)&Qs[(wave * 16 + ln16) * LDSS + kk2 * 32 + quad * 8];
            #pragma unroll
            for (int t = 0; t < 4; ++t) {
                short8 bf = *(const short8*)&Ks[(t * 16 + ln16) * LDSS + kk2 * 32 + quad * 8];
                sv[t] = __builtin_amdgcn_mfma_f32_16x16x32_bf16(af, bf, sv[t], 0, 0, 0);
            }
        }

        float sc[4][4];
        #pragma unroll
        for (int t = 0; t < 4; ++t)
            #pragma unroll
            for (int r = 0; r < 4; ++r)
                sc[t][r] = sv[t][r] * 0.125f;
        if (kt == qt) {
            #pragma unroll
            for (int t = 0; t < 4; ++t) {
                int key = t * 16 + ln16;
                #pragma unroll
                for (int r = 0; r < 4; ++r)
                    if (key > wave * 16 + quad * 4 + r) sc[t][r] = -1e30f;
            }
        }

        float alpha[4];
        #pragma unroll
        for (int r = 0; r < 4; ++r) {
            float mx = fmaxf(fmaxf(sc[0][r], sc[1][r]), fmaxf(sc[2][r], sc[3][r]));
            #pragma unroll
            for (int off = 1; off < 16; off <<= 1)
                mx = fmaxf(mx, __shfl_xor(mx, off, 64));
            float mnew = fmaxf(m_r[r], mx);
            alpha[r] = __expf(m_r[r] - mnew);
            m_r[r] = mnew;
            float srow = 0.f;
            #pragma unroll
            for (int t = 0; t < 4; ++t) {
                float e = __expf(sc[t][r] - mnew);
                sc[t][r] = e;
                srow += e;
            }
            #pragma unroll
            for (int off = 1; off < 16; off <<= 1)
                srow += __shfl_xor(srow, off, 64);
            l_r[r] = l_r[r] * alpha[r] + srow;
        }

        #pragma unroll
        for (int t = 0; t < 4; ++t)
            #pragma unroll
            for (int r = 0; r < 4; ++r)
                Pw[(quad * 4 + r) * LDSS + t * 16 + ln16] = f2b(sc[t][r]);

        #pragma unroll
        for (int t = 0; t < 4; ++t)
            #pragma unroll
            for (int r = 0; r < 4; ++r)
                oacc[t][r] *= alpha[r];

        #pragma unroll
        for (int kk2 = 0; kk2 < 2; ++kk2) {
            short8 pf = *(const short8*)&Pw[ln16 * LDSS + kk2 * 32 + quad * 8];
            #pragma unroll
            for (int t = 0; t < 4; ++t) {
                short8 vf = *(const short8*)&Vs[(t * 16 + ln16) * LDSS + kk2 * 32 + quad * 8];
                oacc[t] = __builtin_amdgcn_mfma_f32_16x16x32_bf16(pf, vf, oacc[t], 0, 0, 0);
            }
        }
        __syncthreads();
    }

    float inv[4];
    #pragma unroll
    for (int r = 0; r < 4; ++r) inv[r] = 1.0f / l_r[r];
    #pragma unroll
    for (int t = 0; t < 4; ++t) {
        #pragma unroll
        for (int r = 0; r < 4; ++r) {
            int row = qt * 64 + wave * 16 + quad * 4 + r;
            int d   = t * 16 + ln16;
            o[((size_t)(b * TSEQ + row)) * CDIM + h * HDIM + d] = f2b(oacc[t][r] * inv[r]);
        }
    }
}

// ---------------------------------------------------------------------------
extern "C" void kernel_launch(void* const* d_in, const int* in_sizes, int n_in,
                              void* d_out, int out_size, void* d_ws, size_t ws_size,
                              hipStream_t stream)
{
    const float* x  = (const float*)d_in[0];
    const float* Wq = (const float*)d_in[1];
    const float* bq = (const float*)d_in[2];
    const float* Wk = (const float*)d_in[3];
    const float* bk = (const float*)d_in[4];
    const float* Wv = (const float*)d_in[5];
    const float* bv = (const float*)d_in[6];
    const float* Wo = (const float*)d_in[7];
    const float* bo = (const float*)d_in[8];
    float* out = (float*)d_out;

    const size_t MB = 1u << 20;
    char* w = (char*)d_ws;
    // xb (bf16 x) aliased with aob (bf16 attention out): xb dead before flash.
    u16*   xb   = (u16*)(w);                     //  8 MB  [BT][1024] bf16
    u16*   aob  = (u16*)(w);                     //  alias
    float* qf   = (float*)(w + 8 * MB);          // 16 MB  [BT][1024] fp32
    float* kvf  = (float*)(w + 24 * MB);         //  2 MB  [BT][128]  fp32
    u16*   Wqt  = (u16*)(w + 26 * MB);           //  2 MB  [1024][1024]
    u16*   Wot  = (u16*)(w + 28 * MB);           //  2 MB
    u16*   Wkvt = (u16*)(w + 30 * MB);           // .25 MB [128][1024]
    float* bkv  = (float*)(w + 30 * MB + 256 * 1024);  // 512 B

    dim3 blk(256);

    // casts / transposes
    cast_bf16_kernel<<<dim3(BT * CDIM / 4 / 256), blk, 0, stream>>>(x, xb, BT * CDIM / 4);
    transpose_cast_kernel<<<dim3(16, 16), blk, 0, stream>>>(Wq, Wqt, CDIM, CDIM, 0);
    transpose_cast_kernel<<<dim3(16, 16), blk, 0, stream>>>(Wo, Wot, CDIM, CDIM, 0);
    transpose_cast_kernel<<<dim3(1, 16),  blk, 0, stream>>>(Wk, Wkvt, CDIM, HDIM, 0);
    transpose_cast_kernel<<<dim3(1, 16),  blk, 0, stream>>>(Wv, Wkvt, CDIM, HDIM, 64);
    concat_bias_kernel<<<1, 128, 0, stream>>>(bk, bv, bkv);

    // projections
    gemm_mfma_kernel<<<dim3(CDIM / 128, BT / 64), blk, 0, stream>>>(
        xb, Wqt, bq, qf, BT, CDIM, CDIM);
    gemm_mfma_kernel<<<dim3(1, BT / 64), blk, 0, stream>>>(
        xb, Wkvt, bkv, kvf, BT, 128, CDIM);

    // RoPE
    rope_kernel<<<dim3(BT * NHEAD * 32 / 256), blk, 0, stream>>>(
        qf, NHEAD, CDIM, BT * NHEAD * 32);
    rope_kernel<<<dim3(BT * 32 / 256), blk, 0, stream>>>(
        kvf, 1, 128, BT * 32);

    // attention (writes bf16 aob over xb — xb no longer needed)
    flash_mfma_kernel<<<dim3(TSEQ / 64, NHEAD, BSZ), blk, 0, stream>>>(qf, kvf, aob);

    // output projection
    gemm_mfma_kernel<<<dim3(CDIM / 128, BT / 64), blk, 0, stream>>>(
        aob, Wot, bo, out, BT, CDIM, CDIM);
}

// Round 4
// 240.599 us; speedup vs baseline: 4.9704x; 1.5272x over previous
//
#include <hip/hip_runtime.h>
#include <math.h>

#define BSZ   2
#define TSEQ  2048
#define CDIM  1024
#define NHEAD 16
#define HDIM  64
#define BT    (BSZ*TSEQ)
#define NQKV  1152   // 1024 q + 64 k + 64 v

typedef __attribute__((ext_vector_type(8))) short short8;
typedef __attribute__((ext_vector_type(4))) float f32x4;
typedef unsigned short u16;
typedef unsigned int   u32;

__device__ __forceinline__ u16 f2b(float f) {
    union { float f; u32 u; } c; c.f = f;
    u32 u = c.u;
    u += 0x7fffu + ((u >> 16) & 1u);   // round-nearest-even
    return (u16)(u >> 16);
}
__device__ __forceinline__ u32 pack2(float lo, float hi) {
    return (u32)f2b(lo) | ((u32)f2b(hi) << 16);
}

// async global->LDS, 16B per lane. LDS dest must be wave-uniform base + lane*16.
__device__ __forceinline__ void async_copy16(const void* g, void* l) {
    __builtin_amdgcn_global_load_lds(
        (__attribute__((address_space(1))) const void*)g,
        (__attribute__((address_space(3))) void*)l,
        16, 0, 0);
}

// ---------------------------------------------------------------------------
__global__ __launch_bounds__(256) void cast_bf16_kernel(
    const float* __restrict__ src, u16* __restrict__ dst, int n4)
{
    int i = blockIdx.x * 256 + threadIdx.x;
    if (i >= n4) return;
    float4 f = ((const float4*)src)[i];
    u16* d = dst + (size_t)i * 4;
    d[0] = f2b(f.x); d[1] = f2b(f.y); d[2] = f2b(f.z); d[3] = f2b(f.w);
}

// W [K][Nw] fp32 -> Wt [nofs+n][K] bf16 (transpose + cast)
__global__ __launch_bounds__(256) void transpose_cast_kernel(
    const float* __restrict__ W, u16* __restrict__ Wt,
    int K, int Nw, int nofs)
{
    __shared__ float T[64][65];
    const int tid = threadIdx.x;
    const int k0 = blockIdx.y * 64, n0 = blockIdx.x * 64;
    #pragma unroll
    for (int i = 0; i < 16; ++i) {
        int idx = i * 256 + tid, r = idx >> 6, c = idx & 63;
        T[r][c] = W[(size_t)(k0 + r) * Nw + n0 + c];
    }
    __syncthreads();
    #pragma unroll
    for (int i = 0; i < 16; ++i) {
        int idx = i * 256 + tid, rn = idx >> 6, ck = idx & 63;
        Wt[(size_t)(nofs + n0 + rn) * K + k0 + ck] = f2b(T[ck][rn]);
    }
}

__global__ __launch_bounds__(256) void concat_bias3_kernel(
    const float* __restrict__ bq, const float* __restrict__ bk,
    const float* __restrict__ bv, float* __restrict__ bqkv)
{
    int i = blockIdx.x * 256 + threadIdx.x;
    if (i >= NQKV) return;
    bqkv[i] = (i < 1024) ? bq[i] : (i < 1088 ? bk[i - 1024] : bv[i - 1088]);
}

// ---------------------------------------------------------------------------
// Y[M][N] fp32 = A[M][K](bf16) @ Bt[N][K](bf16)^T + bias.  (verified R3)
// ---------------------------------------------------------------------------
__global__ __launch_bounds__(256) void gemm_mfma_kernel(
    const u16* __restrict__ A, const u16* __restrict__ Bt,
    const float* __restrict__ bias, float* __restrict__ Y,
    int M, int N, int K)
{
    __shared__ __align__(16) u16 AsC[64 * 32];
    __shared__ __align__(16) u16 BsC[128 * 32];
    const int tid  = threadIdx.x;
    const int wave = tid >> 6, lane = tid & 63;
    const int ln16 = lane & 15, quad = lane >> 4;
    const int wm = wave >> 1, wn = wave & 1;
    const int m0 = blockIdx.y * 64, n0 = blockIdx.x * 128;

    const int c_row = ((tid >> 6) << 4) + (tid & 15);
    const int c_k   = ((tid >> 4) & 3) * 8;
    const u16* ag  = &A [(size_t)(m0 + c_row)       * K + c_k];
    const u16* bg0 = &Bt[(size_t)(n0 + c_row)       * K + c_k];
    const u16* bg1 = &Bt[(size_t)(n0 + 64 + c_row)  * K + c_k];
    u16* a_l  = &AsC[(size_t)wave * 64 * 8];
    u16* b_l0 = &BsC[(size_t)wave * 64 * 8];
    u16* b_l1 = &BsC[(size_t)(wave + 4) * 64 * 8];

    f32x4 acc[2][4];
    #pragma unroll
    for (int i = 0; i < 2; ++i)
        #pragma unroll
        for (int j = 0; j < 4; ++j) acc[i][j] = (f32x4){0.f, 0.f, 0.f, 0.f};

    for (int k0 = 0; k0 < K; k0 += 32) {
        async_copy16(ag,  a_l);
        async_copy16(bg0, b_l0);
        async_copy16(bg1, b_l1);
        ag += 32; bg0 += 32; bg1 += 32;
        __syncthreads();

        short8 af[2], bf[4];
        #pragma unroll
        for (int mt = 0; mt < 2; ++mt)
            af[mt] = *(const short8*)&AsC[(((wm * 2 + mt) * 64) + quad * 16 + ln16) * 8];
        #pragma unroll
        for (int nt = 0; nt < 4; ++nt)
            bf[nt] = *(const short8*)&BsC[(((wn * 4 + nt) * 64) + quad * 16 + ln16) * 8];
        #pragma unroll
        for (int mt = 0; mt < 2; ++mt)
            #pragma unroll
            for (int nt = 0; nt < 4; ++nt)
                acc[mt][nt] = __builtin_amdgcn_mfma_f32_16x16x32_bf16(
                    af[mt], bf[nt], acc[mt][nt], 0, 0, 0);
        __syncthreads();
    }

    #pragma unroll
    for (int mt = 0; mt < 2; ++mt)
        #pragma unroll
        for (int nt = 0; nt < 4; ++nt) {
            int n = n0 + wn * 64 + nt * 16 + ln16;
            float bb = bias[n];
            #pragma unroll
            for (int r = 0; r < 4; ++r) {
                int m = m0 + wm * 32 + mt * 16 + quad * 4 + r;
                Y[(size_t)m * N + n] = acc[mt][nt][r] + bb;
            }
        }
}

// ---------------------------------------------------------------------------
// RoPE for q (heads 0..15 -> qb, pre-scaled 1/8) and k (slot 16 -> kb), bf16.
// Each thread handles a j-pair (j=2p, 2p+1) of one (bt, head-slot).
// ---------------------------------------------------------------------------
__global__ __launch_bounds__(256) void rope_qk_kernel(
    const float* __restrict__ qkvf, u16* __restrict__ qb, u16* __restrict__ kb)
{
    int idx = blockIdx.x * 256 + threadIdx.x;
    const int total = BT * 17 * 16;
    if (idx >= total) return;
    int p4  = idx & 15;
    int rest = idx >> 4;
    int hh  = rest % 17;
    int bt  = rest / 17;
    int j   = p4 * 2;
    int tpos = bt & (TSEQ - 1);
    float f0 = exp2f(-0.41524101186092029f * (float)j);        // 10000^(-j/32)
    float f1 = exp2f(-0.41524101186092029f * (float)(j + 1));
    float a0s, a0c, a1s, a1c;
    __sincosf((float)tpos * f0, &a0s, &a0c);
    __sincosf((float)tpos * f1, &a1s, &a1c);
    const float* base = qkvf + (size_t)bt * NQKV + hh * 64;
    float t10 = base[j],      t11 = base[j + 1];
    float t20 = base[j + 32], t21 = base[j + 33];
    float lo0 = fmaf(t10, a0c, t20 * a0s), lo1 = fmaf(t11, a1c, t21 * a1s);
    float hi0 = fmaf(t10, a0s, -t20 * a0c), hi1 = fmaf(t11, a1s, -t21 * a1c);
    if (hh < 16) {   // q: scale by 1/8 (exact pow2; folds softmax 1/sqrt(64))
        u16* o = qb + (size_t)bt * CDIM + hh * 64 + j;
        *(u32*)o        = pack2(lo0 * 0.125f, lo1 * 0.125f);
        *(u32*)(o + 32) = pack2(hi0 * 0.125f, hi1 * 0.125f);
    } else {         // k
        u16* o = kb + (size_t)bt * HDIM + j;
        *(u32*)o        = pack2(lo0, lo1);
        *(u32*)(o + 32) = pack2(hi0, hi1);
    }
}

// ---------------------------------------------------------------------------
// v slice of qkvf [bt][1088+d] fp32 -> vT [b][d][T] bf16 (64x64 LDS tile)
// ---------------------------------------------------------------------------
__global__ __launch_bounds__(256) void transpose_v_kernel(
    const float* __restrict__ qkvf, u16* __restrict__ vT)
{
    __shared__ float T[64][65];
    const int tid = threadIdx.x;
    const int b  = blockIdx.y;
    const int t0 = blockIdx.x * 64;
    #pragma unroll
    for (int i = 0; i < 16; ++i) {
        int idx = i * 256 + tid, r = idx >> 6, c = idx & 63;
        T[r][c] = qkvf[(size_t)(b * TSEQ + t0 + r) * NQKV + 1088 + c];
    }
    __syncthreads();
    #pragma unroll
    for (int i = 0; i < 8; ++i) {
        int idx = i * 256 + tid;           // 0..2047  (uint pairs)
        int d = idx >> 5, tp = idx & 31;
        u32 u = pack2(T[tp * 2][d], T[tp * 2 + 1][d]);
        *(u32*)&vT[(size_t)(b * HDIM + d) * TSEQ + t0 + tp * 2] = u;
    }
}

// ---------------------------------------------------------------------------
// MFMA flash attention, balanced pairs + async bf16 staging.
// Block p handles qt = p and qt = 31-p  (exactly 33 k-tiles each).
// LDS tiles chunk-ordered (16B chunk c -> [tilegrp][kk2][quad][ln16]):
//   row(c) = ((c>>7)<<4)|(c&15),  off(c) = ((c>>6)&1)*32 + ((c>>4)&3)*8
// so staging dest is lane-linear (HW req) AND frag ds_read_b128 lane-linear.
// q pre-scaled by 1/8 in rope_qk, so S needs no scaling here.
// ---------------------------------------------------------------------------
__global__ __launch_bounds__(256) void flash_mfma_kernel(
    const u16* __restrict__ qb, const u16* __restrict__ kb,
    const u16* __restrict__ vT, u16* __restrict__ o)
{
    const int id = blockIdx.x;
    const int p  = id & 15;
    const int h  = (id >> 4) & 15;
    const int b  = id >> 8;
    __shared__ __align__(16) u16 Qs[512 * 8];        // 8 KB
    __shared__ __align__(16) u16 Ks[512 * 8];        // 8 KB
    __shared__ __align__(16) u16 Vs[512 * 8];        // 8 KB
    __shared__ __align__(16) u16 Ps[4 * 16 * 72];    // 9 KB, per-wave [16][72]

    const int tid  = threadIdx.x;
    const int wave = tid >> 6, lane = tid & 63;
    const int ln16 = lane & 15, quad = lane >> 4;

    // this thread's two staging chunks (c and c+256) -> global (row, offset)
    const int c0   = tid;
    int row_c[2], off_c[2];
    #pragma unroll
    for (int hf = 0; hf < 2; ++hf) {
        int c = c0 + hf * 256;
        row_c[hf] = ((c >> 7) << 4) | (c & 15);
        off_c[hf] = ((c >> 6) & 1) * 32 + ((c >> 4) & 3) * 8;
    }

    u16* Pw = &Ps[wave * 16 * 72];

    for (int s = 0; s < 2; ++s) {
        const int qt = s ? (31 - p) : p;

        // ---- stage Q (2 async chunks/thread) ----
        #pragma unroll
        for (int hf = 0; hf < 2; ++hf)
            async_copy16(
                qb + (size_t)(b * TSEQ + qt * 64 + row_c[hf]) * CDIM + h * HDIM + off_c[hf],
                Qs + (c0 + hf * 256) * 8);

        float m_r[4], l_r[4];
        f32x4 oacc[4];
        #pragma unroll
        for (int r = 0; r < 4; ++r) { m_r[r] = -1e30f; l_r[r] = 0.f; }
        #pragma unroll
        for (int t = 0; t < 4; ++t) oacc[t] = (f32x4){0.f, 0.f, 0.f, 0.f};

        for (int kt = 0; kt <= qt; ++kt) {
            const size_t kt0 = (size_t)(b * TSEQ + kt * 64);
            #pragma unroll
            for (int hf = 0; hf < 2; ++hf) {
                int cc = c0 + hf * 256;
                async_copy16(kb + (kt0 + row_c[hf]) * HDIM + off_c[hf], Ks + cc * 8);
                async_copy16(vT + (size_t)(b * HDIM + row_c[hf]) * TSEQ + kt * 64 + off_c[hf],
                             Vs + cc * 8);
            }
            __syncthreads();   // drains vmcnt (incl. Q on first iter)

            // ---- S = Q.K^T ----
            f32x4 sv[4];
            #pragma unroll
            for (int t = 0; t < 4; ++t) sv[t] = (f32x4){0.f, 0.f, 0.f, 0.f};
            #pragma unroll
            for (int kk2 = 0; kk2 < 2; ++kk2) {
                short8 af = *(const short8*)&Qs[(wave * 128 + kk2 * 64 + quad * 16 + ln16) * 8];
                #pragma unroll
                for (int t = 0; t < 4; ++t) {
                    short8 bf = *(const short8*)&Ks[(t * 128 + kk2 * 64 + quad * 16 + ln16) * 8];
                    sv[t] = __builtin_amdgcn_mfma_f32_16x16x32_bf16(af, bf, sv[t], 0, 0, 0);
                }
            }

            // ---- causal mask (diag tile only; q pre-scaled) ----
            float sc[4][4];
            #pragma unroll
            for (int t = 0; t < 4; ++t)
                #pragma unroll
                for (int r = 0; r < 4; ++r) sc[t][r] = sv[t][r];
            if (kt == qt) {
                #pragma unroll
                for (int t = 0; t < 4; ++t) {
                    int key = t * 16 + ln16;
                    #pragma unroll
                    for (int r = 0; r < 4; ++r)
                        if (key > wave * 16 + quad * 4 + r) sc[t][r] = -1e30f;
                }
            }

            // ---- online softmax (quad-row lives across 16 lanes) ----
            float alpha[4];
            #pragma unroll
            for (int r = 0; r < 4; ++r) {
                float mx = fmaxf(fmaxf(sc[0][r], sc[1][r]), fmaxf(sc[2][r], sc[3][r]));
                #pragma unroll
                for (int off = 1; off < 16; off <<= 1)
                    mx = fmaxf(mx, __shfl_xor(mx, off, 64));
                float mnew = fmaxf(m_r[r], mx);
                alpha[r] = __expf(m_r[r] - mnew);
                m_r[r] = mnew;
                float srow = 0.f;
                #pragma unroll
                for (int t = 0; t < 4; ++t) {
                    float e = __expf(sc[t][r] - mnew);
                    sc[t][r] = e;
                    srow += e;
                }
                #pragma unroll
                for (int off = 1; off < 16; off <<= 1)
                    srow += __shfl_xor(srow, off, 64);
                l_r[r] = l_r[r] * alpha[r] + srow;
            }

            // ---- P: C-layout -> per-wave LDS (A-layout source) ----
            #pragma unroll
            for (int t = 0; t < 4; ++t)
                #pragma unroll
                for (int r = 0; r < 4; ++r)
                    Pw[(quad * 4 + r) * 72 + t * 16 + ln16] = f2b(sc[t][r]);

            #pragma unroll
            for (int t = 0; t < 4; ++t)
                #pragma unroll
                for (int r = 0; r < 4; ++r)
                    oacc[t][r] *= alpha[r];

            // ---- O += P.V ----
            #pragma unroll
            for (int kk2 = 0; kk2 < 2; ++kk2) {
                short8 pf = *(const short8*)&Pw[ln16 * 72 + kk2 * 32 + quad * 8];
                #pragma unroll
                for (int t = 0; t < 4; ++t) {
                    short8 vf = *(const short8*)&Vs[(t * 128 + kk2 * 64 + quad * 16 + ln16) * 8];
                    oacc[t] = __builtin_amdgcn_mfma_f32_16x16x32_bf16(pf, vf, oacc[t], 0, 0, 0);
                }
            }
            __syncthreads();   // before next tile's staging overwrites LDS
        }

        // ---- epilogue ----
        float inv[4];
        #pragma unroll
        for (int r = 0; r < 4; ++r) inv[r] = 1.0f / l_r[r];
        #pragma unroll
        for (int t = 0; t < 4; ++t) {
            #pragma unroll
            for (int r = 0; r < 4; ++r) {
                int row = qt * 64 + wave * 16 + quad * 4 + r;
                int d   = t * 16 + ln16;
                o[(size_t)(b * TSEQ + row) * CDIM + h * HDIM + d] = f2b(oacc[t][r] * inv[r]);
            }
        }
    }
}

// ---------------------------------------------------------------------------
extern "C" void kernel_launch(void* const* d_in, const int* in_sizes, int n_in,
                              void* d_out, int out_size, void* d_ws, size_t ws_size,
                              hipStream_t stream)
{
    const float* x  = (const float*)d_in[0];
    const float* Wq = (const float*)d_in[1];
    const float* bq = (const float*)d_in[2];
    const float* Wk = (const float*)d_in[3];
    const float* bk = (const float*)d_in[4];
    const float* Wv = (const float*)d_in[5];
    const float* bv = (const float*)d_in[6];
    const float* Wo = (const float*)d_in[7];
    const float* bo = (const float*)d_in[8];
    float* out = (float*)d_out;

    const size_t MB = 1u << 20;
    char* w = (char*)d_ws;
    // xb dead after qkv GEMM -> qb aliases xb. qkvf dead after rope/transpose
    // -> aob aliases qkvf head. Total footprint ~32 MB.
    u16*   xb   = (u16*)(w);                   //  8 MB [BT][1024] bf16
    u16*   qb   = (u16*)(w);                   //  alias (rope'd q, pre-scaled)
    float* qkvf = (float*)(w + 8 * MB);        // 18 MB [BT][1152] fp32
    u16*   aob  = (u16*)(w + 8 * MB);          //  alias, 8 MB [BT][1024] bf16
    u16*   Wqkvt= (u16*)(w + 26 * MB);         //  2.25 MB [1152][1024]
    u16*   Wot  = (u16*)(w + 29 * MB);         //  2 MB
    u16*   kb   = (u16*)(w + 31 * MB);         //  0.5 MB [BT][64]
    u16*   vT   = (u16*)(w + 31 * MB + 512 * 1024);   // 0.5 MB [B][64][T]
    float* bqkv = (float*)(w + 32 * MB);       //  4.5 KB

    dim3 blk(256);

    cast_bf16_kernel<<<dim3(BT * CDIM / 4 / 256), blk, 0, stream>>>(x, xb, BT * CDIM / 4);
    transpose_cast_kernel<<<dim3(16, 16), blk, 0, stream>>>(Wq, Wqkvt, CDIM, CDIM, 0);
    transpose_cast_kernel<<<dim3(1, 16),  blk, 0, stream>>>(Wk, Wqkvt, CDIM, HDIM, 1024);
    transpose_cast_kernel<<<dim3(1, 16),  blk, 0, stream>>>(Wv, Wqkvt, CDIM, HDIM, 1088);
    transpose_cast_kernel<<<dim3(16, 16), blk, 0, stream>>>(Wo, Wot, CDIM, CDIM, 0);
    concat_bias3_kernel<<<dim3(5), blk, 0, stream>>>(bq, bk, bv, bqkv);

    // fused q|k|v projection: [BT][1152]
    gemm_mfma_kernel<<<dim3(NQKV / 128, BT / 64), blk, 0, stream>>>(
        xb, Wqkvt, bqkv, qkvf, BT, NQKV, CDIM);

    // rope -> bf16 q (scaled 1/8) + bf16 k ; v transpose -> bf16 vT
    rope_qk_kernel<<<dim3(BT * 17 * 16 / 256), blk, 0, stream>>>(qkvf, qb, kb);
    transpose_v_kernel<<<dim3(TSEQ / 64, BSZ), blk, 0, stream>>>(qkvf, vT);

    // balanced flash attention -> aob (overwrites dead qkvf head)
    flash_mfma_kernel<<<dim3(16 * NHEAD * BSZ), blk, 0, stream>>>(qb, kb, vT, aob);

    // output projection
    gemm_mfma_kernel<<<dim3(CDIM / 128, BT / 64), blk, 0, stream>>>(
        aob, Wot, bo, out, BT, CDIM, CDIM);
}